// Round 10
// baseline (1154.154 us; speedup 1.0000x reference)
//
#include <hip/hip_runtime.h>
#include <cmath>

#define NLV 16
static constexpr unsigned T_SIZE = 1u << 19;
static constexpr unsigned T_MASK = T_SIZE - 1u;

struct ScaleArgs { float s[NLV]; };

typedef float v2f __attribute__((ext_vector_type(2)));
typedef float v4f __attribute__((ext_vector_type(4)));

__device__ __forceinline__ void nt_store2(float2 v, float2* p) {
    v2f x; x[0] = v.x; x[1] = v.y;
    __builtin_nontemporal_store(x, (v2f*)p);
}
__device__ __forceinline__ float2 nt_load2(const float2* p) {
    v2f x = __builtin_nontemporal_load((const v2f*)p);
    return make_float2(x[0], x[1]);
}
__device__ __forceinline__ void nt_store4(float4 v, float4* p) {
    v4f x; x[0] = v.x; x[1] = v.y; x[2] = v.z; x[3] = v.w;
    __builtin_nontemporal_store(x, (v4f*)p);
}

// Load table entries i0 and i1 via their aligned float4 pairs. When i1 is in
// the same 16B pair as i0 (dense even base; hashed even-x: h(x+1)=h(x)^1),
// the second load is a same-line L1/MSHR hit -> one L2 request instead of two.
__device__ __forceinline__ void pair_load(const float4* __restrict__ t4,
                                          unsigned i0, unsigned i1,
                                          float2& c0, float2& c1) {
    const float4 a = t4[i0 >> 1];
    const float4 b = t4[i1 >> 1];
    c0 = (i0 & 1u) ? make_float2(a.z, a.w) : make_float2(a.x, a.y);
    c1 = (i1 & 1u) ? make_float2(b.z, b.w) : make_float2(b.x, b.y);
}

__device__ __forceinline__ float3 normalize_pt(const float* __restrict__ p,
                                               const float* __restrict__ aabb, int i) {
    const float a0x = aabb[0], a0y = aabb[1], a0z = aabb[2];
    const float a1x = aabb[3], a1y = aabb[4], a1z = aabb[5];
    const float px = p[3 * i + 0], py = p[3 * i + 1], pz = p[3 * i + 2];
    float3 r;
    r.x = fminf(fmaxf((px - a0x) / (a1x - a0x), 0.0f), 1.0f);
    r.y = fminf(fmaxf((py - a0y) / (a1y - a0y), 0.0f), 1.0f);
    r.z = fminf(fmaxf((pz - a0z) / (a1z - a0z), 0.0f), 1.0f);
    return r;
}

// trilinear accumulate helper (same op order as reference)
__device__ __forceinline__ void tri_acc(
    float2 c0, float2 c1, float2 c2, float2 c3,
    float2 c4, float2 c5, float2 c6, float2 c7,
    float fx, float fy, float fz, float& f0, float& f1)
{
    const float wx0 = 1.0f - fx, wy0 = 1.0f - fy, wz0 = 1.0f - fz;
    const float w00 = wx0 * wy0, w10 = fx * wy0, w01 = wx0 * fy, w11 = fx * fy;
    const float wa = w00 * wz0, wb = w10 * wz0, wc = w01 * wz0, wd = w11 * wz0;
    const float we = w00 * fz,  wf = w10 * fz,  wg = w01 * fz,  wh = w11 * fz;

    f0 = wa * c0.x; f1 = wa * c0.y;
    f0 = fmaf(wb, c1.x, f0); f1 = fmaf(wb, c1.y, f1);
    f0 = fmaf(wc, c2.x, f0); f1 = fmaf(wc, c2.y, f1);
    f0 = fmaf(wd, c3.x, f0); f1 = fmaf(wd, c3.y, f1);
    f0 = fmaf(we, c4.x, f0); f1 = fmaf(we, c4.y, f1);
    f0 = fmaf(wf, c5.x, f0); f1 = fmaf(wf, c5.y, f1);
    f0 = fmaf(wg, c6.x, f0); f1 = fmaf(wg, c6.y, f1);
    f0 = fmaf(wh, c7.x, f0); f1 = fmaf(wh, c7.y, f1);
}

// ---- dense levels 0..4 (tables total 4.3 MB -> L2-resident) ----
__global__ void __launch_bounds__(256) dense_encode_kernel(
    const float* __restrict__ p, const float* __restrict__ aabb,
    const float* __restrict__ table, float2* __restrict__ enc,
    int N, ScaleArgs sa)
{
    const int i = blockIdx.x * 256 + threadIdx.x;
    if (i >= N) return;
    const float3 u = normalize_pt(p, aabb, i);

    constexpr int DENSE_RES[5] = {16, 24, 34, 49, 71};
#pragma unroll
    for (int l = 0; l < 5; ++l) {
        const float s = sa.s[l];
        const float posx = u.x * s + 0.5f;
        const float posy = u.y * s + 0.5f;
        const float posz = u.z * s + 0.5f;
        const float flx = floorf(posx), fly = floorf(posy), flz = floorf(posz);
        const float fx = posx - flx, fy = posy - fly, fz = posz - flz;
        const int ix = (int)flx, iy = (int)fly, iz = (int)flz;

        const int res = DENSE_RES[l];
        const unsigned b  = (unsigned)(ix + res * (iy + res * iz));
        const unsigned dy = (unsigned)res;
        const unsigned dz = (unsigned)(res * res);

        const float4* __restrict__ t4 = reinterpret_cast<const float4*>(
            reinterpret_cast<const float2*>(table) + (size_t)l * T_SIZE);

        float2 c0, c1, c2, c3, c4, c5, c6, c7;
        pair_load(t4, b,           b + 1u,           c0, c1);
        pair_load(t4, b + dy,      b + dy + 1u,      c2, c3);
        pair_load(t4, b + dz,      b + dz + 1u,      c4, c5);
        pair_load(t4, b + dy + dz, b + dy + dz + 1u, c6, c7);

        float f0, f1;
        tri_acc(c0, c1, c2, c3, c4, c5, c6, c7, fx, fy, fz, f0, f1);
        nt_store2(make_float2(f0, f1), &enc[(size_t)l * N + i]);
    }
}

// ---- one hashed level per launch: 4 MiB slice == one XCD L2, phased ----
template<int L>
__global__ void __launch_bounds__(256) hash_encode_kernel(
    const float* __restrict__ p, const float* __restrict__ aabb,
    const float* __restrict__ table, float2* __restrict__ enc,
    int N, float s)
{
    const int i = blockIdx.x * 256 + threadIdx.x;
    if (i >= N) return;
    const float3 u = normalize_pt(p, aabb, i);

    const float posx = u.x * s + 0.5f;
    const float posy = u.y * s + 0.5f;
    const float posz = u.z * s + 0.5f;
    const float flx = floorf(posx), fly = floorf(posy), flz = floorf(posz);
    const float fx = posx - flx, fy = posy - fly, fz = posz - flz;
    const int ix = (int)flx, iy = (int)fly, iz = (int)flz;

    const unsigned hx0 = (unsigned)ix,               hx1 = hx0 + 1u;
    const unsigned hy0 = (unsigned)iy * 2654435761u, hy1 = hy0 + 2654435761u;
    const unsigned hz0 = (unsigned)iz * 805459861u,  hz1 = hz0 + 805459861u;
    const unsigned idx0 = (hx0 ^ hy0 ^ hz0) & T_MASK;
    const unsigned idx1 = (hx1 ^ hy0 ^ hz0) & T_MASK;
    const unsigned idx2 = (hx0 ^ hy1 ^ hz0) & T_MASK;
    const unsigned idx3 = (hx1 ^ hy1 ^ hz0) & T_MASK;
    const unsigned idx4 = (hx0 ^ hy0 ^ hz1) & T_MASK;
    const unsigned idx5 = (hx1 ^ hy0 ^ hz1) & T_MASK;
    const unsigned idx6 = (hx0 ^ hy1 ^ hz1) & T_MASK;
    const unsigned idx7 = (hx1 ^ hy1 ^ hz1) & T_MASK;

    const float4* __restrict__ t4 = reinterpret_cast<const float4*>(
        reinterpret_cast<const float2*>(table) + (size_t)L * T_SIZE);

    float2 c0, c1, c2, c3, c4, c5, c6, c7;
    pair_load(t4, idx0, idx1, c0, c1);  // even ix: idx1 = idx0^1 -> same 16B pair
    pair_load(t4, idx2, idx3, c2, c3);
    pair_load(t4, idx4, idx5, c4, c5);
    pair_load(t4, idx6, idx7, c6, c7);

    float f0, f1;
    tri_acc(c0, c1, c2, c3, c4, c5, c6, c7, fx, fy, fz, f0, f1);
    nt_store2(make_float2(f0, f1), &enc[(size_t)L * N + i]);
}

// ---- MLP over staged features ----
__global__ void __launch_bounds__(256) mlp_kernel(
    const float2* __restrict__ enc,
    const float* __restrict__ w1, const float* __restrict__ w2,
    const float* __restrict__ w3, float* __restrict__ out, int N)
{
    const int i = blockIdx.x * 256 + threadIdx.x;
    if (i >= N) return;

    float e[32];
#pragma unroll
    for (int l = 0; l < NLV; ++l) {
        const float2 v = nt_load2(&enc[(size_t)l * N + i]);
        e[2 * l] = v.x; e[2 * l + 1] = v.y;
    }

    float h[32];
#pragma unroll
    for (int j = 0; j < 32; ++j) {
        float acc = 0.0f;
#pragma unroll
        for (int k = 0; k < 32; ++k) acc = fmaf(w1[32 * j + k], e[k], acc);
        h[j] = fmaxf(acc, 0.0f);
    }
    float g[32];
#pragma unroll
    for (int j = 0; j < 32; ++j) {
        float acc = 0.0f;
#pragma unroll
        for (int k = 0; k < 32; ++k) acc = fmaf(w2[32 * j + k], h[k], acc);
        g[j] = fmaxf(acc, 0.0f);
    }
    float o[4];
#pragma unroll
    for (int j = 0; j < 4; ++j) {
        float acc = 0.0f;
#pragma unroll
        for (int k = 0; k < 32; ++k) acc = fmaf(w3[32 * j + k], g[k], acc);
        o[j] = acc;
    }
    nt_store4(make_float4(o[0], o[1], o[2], o[3]),
              &reinterpret_cast<float4*>(out)[i]);
}

// ---- fallback: fused kernel (used only if ws too small) ----
__global__ void __launch_bounds__(256) hashgrid_mlp_kernel(
    const float* __restrict__ p, const float* __restrict__ aabb,
    const float* __restrict__ table,
    const float* __restrict__ w1, const float* __restrict__ w2,
    const float* __restrict__ w3, float* __restrict__ out,
    int N, ScaleArgs sa)
{
    const int i = blockIdx.x * 256 + threadIdx.x;
    if (i >= N) return;
    const float3 u = normalize_pt(p, aabb, i);

    float enc[2 * NLV];
    constexpr int DENSE_RES[5] = {16, 24, 34, 49, 71};
#pragma unroll
    for (int l = 0; l < NLV; ++l) {
        const float s = sa.s[l];
        const float posx = u.x * s + 0.5f;
        const float posy = u.y * s + 0.5f;
        const float posz = u.z * s + 0.5f;
        const float flx = floorf(posx), fly = floorf(posy), flz = floorf(posz);
        const float fx = posx - flx, fy = posy - fly, fz = posz - flz;
        const int ix = (int)flx, iy = (int)fly, iz = (int)flz;

        unsigned idx0, idx1, idx2, idx3, idx4, idx5, idx6, idx7;
        if (l < 5) {
            const int res = DENSE_RES[l];
            const unsigned b  = (unsigned)(ix + res * (iy + res * iz));
            const unsigned dy = (unsigned)res;
            const unsigned dz = (unsigned)(res * res);
            idx0 = b;           idx1 = b + 1u;
            idx2 = b + dy;      idx3 = b + dy + 1u;
            idx4 = b + dz;      idx5 = b + dz + 1u;
            idx6 = b + dy + dz; idx7 = b + dy + dz + 1u;
        } else {
            const unsigned hx0 = (unsigned)ix,               hx1 = hx0 + 1u;
            const unsigned hy0 = (unsigned)iy * 2654435761u, hy1 = hy0 + 2654435761u;
            const unsigned hz0 = (unsigned)iz * 805459861u,  hz1 = hz0 + 805459861u;
            idx0 = (hx0 ^ hy0 ^ hz0) & T_MASK;
            idx1 = (hx1 ^ hy0 ^ hz0) & T_MASK;
            idx2 = (hx0 ^ hy1 ^ hz0) & T_MASK;
            idx3 = (hx1 ^ hy1 ^ hz0) & T_MASK;
            idx4 = (hx0 ^ hy0 ^ hz1) & T_MASK;
            idx5 = (hx1 ^ hy0 ^ hz1) & T_MASK;
            idx6 = (hx0 ^ hy1 ^ hz1) & T_MASK;
            idx7 = (hx1 ^ hy1 ^ hz1) & T_MASK;
        }

        const float4* __restrict__ t4 = reinterpret_cast<const float4*>(
            reinterpret_cast<const float2*>(table) + (size_t)l * T_SIZE);
        float2 c0, c1, c2, c3, c4, c5, c6, c7;
        pair_load(t4, idx0, idx1, c0, c1);
        pair_load(t4, idx2, idx3, c2, c3);
        pair_load(t4, idx4, idx5, c4, c5);
        pair_load(t4, idx6, idx7, c6, c7);

        float f0, f1;
        tri_acc(c0, c1, c2, c3, c4, c5, c6, c7, fx, fy, fz, f0, f1);
        enc[2 * l] = f0; enc[2 * l + 1] = f1;
    }

    float h[32];
#pragma unroll
    for (int j = 0; j < 32; ++j) {
        float acc = 0.0f;
#pragma unroll
        for (int k = 0; k < 32; ++k) acc = fmaf(w1[32 * j + k], enc[k], acc);
        h[j] = fmaxf(acc, 0.0f);
    }
    float g[32];
#pragma unroll
    for (int j = 0; j < 32; ++j) {
        float acc = 0.0f;
#pragma unroll
        for (int k = 0; k < 32; ++k) acc = fmaf(w2[32 * j + k], h[k], acc);
        g[j] = fmaxf(acc, 0.0f);
    }
    float o[4];
#pragma unroll
    for (int j = 0; j < 4; ++j) {
        float acc = 0.0f;
#pragma unroll
        for (int k = 0; k < 32; ++k) acc = fmaf(w3[32 * j + k], g[k], acc);
        o[j] = acc;
    }
    reinterpret_cast<float4*>(out)[i] = make_float4(o[0], o[1], o[2], o[3]);
}

extern "C" void kernel_launch(void* const* d_in, const int* in_sizes, int n_in,
                              void* d_out, int out_size, void* d_ws, size_t ws_size,
                              hipStream_t stream) {
    const float* p     = (const float*)d_in[0];
    const float* aabb  = (const float*)d_in[1];
    const float* table = (const float*)d_in[2];
    const float* w1    = (const float*)d_in[3];
    const float* w2    = (const float*)d_in[4];
    const float* w3    = (const float*)d_in[5];
    float* out = (float*)d_out;
    const int N = in_sizes[0] / 3;

    ScaleArgs sa;
    const double b = exp(log(4096.0 / 16.0) / (double)(NLV - 1));
    for (int l = 0; l < NLV; ++l) sa.s[l] = (float)(16.0 * pow(b, (double)l) - 1.0);

    const int threads = 256;
    const int blocks = (N + threads - 1) / threads;
    const size_t need = (size_t)N * NLV * sizeof(float2);

    if (ws_size >= need) {
        float2* enc = (float2*)d_ws;
        hipLaunchKernelGGL(dense_encode_kernel, dim3(blocks), dim3(threads), 0, stream,
                           p, aabb, table, enc, N, sa);
#define LAUNCH_HASH(L) \
        hipLaunchKernelGGL(hash_encode_kernel<L>, dim3(blocks), dim3(threads), 0, stream, \
                           p, aabb, table, enc, N, sa.s[L])
        LAUNCH_HASH(5);  LAUNCH_HASH(6);  LAUNCH_HASH(7);  LAUNCH_HASH(8);
        LAUNCH_HASH(9);  LAUNCH_HASH(10); LAUNCH_HASH(11); LAUNCH_HASH(12);
        LAUNCH_HASH(13); LAUNCH_HASH(14); LAUNCH_HASH(15);
#undef LAUNCH_HASH
        hipLaunchKernelGGL(mlp_kernel, dim3(blocks), dim3(threads), 0, stream,
                           enc, w1, w2, w3, out, N);
    } else {
        hipLaunchKernelGGL(hashgrid_mlp_kernel, dim3(blocks), dim3(threads), 0, stream,
                           p, aabb, table, w1, w2, w3, out, N, sa);
    }
}

// Round 11
// 952.530 us; speedup vs baseline: 1.2117x; 1.2117x over previous
//
#include <hip/hip_runtime.h>
#include <cmath>

#define NLV 16
static constexpr unsigned T_SIZE = 1u << 19;
static constexpr unsigned T_MASK = T_SIZE - 1u;
static constexpr int NHASH = 11;   // levels 5..15 staged in ws

struct ScaleArgs { float s[NLV]; };

__device__ __forceinline__ float3 normalize_pt(const float* __restrict__ p,
                                               const float* __restrict__ aabb, int i) {
    const float a0x = aabb[0], a0y = aabb[1], a0z = aabb[2];
    const float a1x = aabb[3], a1y = aabb[4], a1z = aabb[5];
    const float px = p[3 * i + 0], py = p[3 * i + 1], pz = p[3 * i + 2];
    float3 r;
    r.x = fminf(fmaxf((px - a0x) / (a1x - a0x), 0.0f), 1.0f);
    r.y = fminf(fmaxf((py - a0y) / (a1y - a0y), 0.0f), 1.0f);
    r.z = fminf(fmaxf((pz - a0z) / (a1z - a0z), 0.0f), 1.0f);
    return r;
}

// trilinear accumulate (same op order as reference)
__device__ __forceinline__ void tri_acc(
    float2 c0, float2 c1, float2 c2, float2 c3,
    float2 c4, float2 c5, float2 c6, float2 c7,
    float fx, float fy, float fz, float& f0, float& f1)
{
    const float wx0 = 1.0f - fx, wy0 = 1.0f - fy, wz0 = 1.0f - fz;
    const float w00 = wx0 * wy0, w10 = fx * wy0, w01 = wx0 * fy, w11 = fx * fy;
    const float wa = w00 * wz0, wb = w10 * wz0, wc = w01 * wz0, wd = w11 * wz0;
    const float we = w00 * fz,  wf = w10 * fz,  wg = w01 * fz,  wh = w11 * fz;

    f0 = wa * c0.x; f1 = wa * c0.y;
    f0 = fmaf(wb, c1.x, f0); f1 = fmaf(wb, c1.y, f1);
    f0 = fmaf(wc, c2.x, f0); f1 = fmaf(wc, c2.y, f1);
    f0 = fmaf(wd, c3.x, f0); f1 = fmaf(wd, c3.y, f1);
    f0 = fmaf(we, c4.x, f0); f1 = fmaf(we, c4.y, f1);
    f0 = fmaf(wf, c5.x, f0); f1 = fmaf(wf, c5.y, f1);
    f0 = fmaf(wg, c6.x, f0); f1 = fmaf(wg, c6.y, f1);
    f0 = fmaf(wh, c7.x, f0); f1 = fmaf(wh, c7.y, f1);
}

// ---- one hashed level per launch: 4 MiB slice == one XCD L2, phased (round-2 form) ----
template<int L>
__global__ void __launch_bounds__(256) hash_encode_kernel(
    const float* __restrict__ p, const float* __restrict__ aabb,
    const float* __restrict__ table, float2* __restrict__ enc,
    int N, float s)
{
    const int i = blockIdx.x * 256 + threadIdx.x;
    if (i >= N) return;
    const float3 u = normalize_pt(p, aabb, i);

    const float posx = u.x * s + 0.5f;
    const float posy = u.y * s + 0.5f;
    const float posz = u.z * s + 0.5f;
    const float flx = floorf(posx), fly = floorf(posy), flz = floorf(posz);
    const float fx = posx - flx, fy = posy - fly, fz = posz - flz;
    const int ix = (int)flx, iy = (int)fly, iz = (int)flz;

    const unsigned hx0 = (unsigned)ix,               hx1 = hx0 + 1u;
    const unsigned hy0 = (unsigned)iy * 2654435761u, hy1 = hy0 + 2654435761u;
    const unsigned hz0 = (unsigned)iz * 805459861u,  hz1 = hz0 + 805459861u;
    const unsigned idx0 = (hx0 ^ hy0 ^ hz0) & T_MASK;
    const unsigned idx1 = (hx1 ^ hy0 ^ hz0) & T_MASK;
    const unsigned idx2 = (hx0 ^ hy1 ^ hz0) & T_MASK;
    const unsigned idx3 = (hx1 ^ hy1 ^ hz0) & T_MASK;
    const unsigned idx4 = (hx0 ^ hy0 ^ hz1) & T_MASK;
    const unsigned idx5 = (hx1 ^ hy0 ^ hz1) & T_MASK;
    const unsigned idx6 = (hx0 ^ hy1 ^ hz1) & T_MASK;
    const unsigned idx7 = (hx1 ^ hy1 ^ hz1) & T_MASK;

    const float2* __restrict__ tl =
        reinterpret_cast<const float2*>(table) + (size_t)L * T_SIZE;
    const float2 c0 = tl[idx0], c1 = tl[idx1], c2 = tl[idx2], c3 = tl[idx3];
    const float2 c4 = tl[idx4], c5 = tl[idx5], c6 = tl[idx6], c7 = tl[idx7];

    float f0, f1;
    tri_acc(c0, c1, c2, c3, c4, c5, c6, c7, fx, fy, fz, f0, f1);
    // slot (L-5): only hashed levels are staged
    enc[(size_t)(L - 5) * N + i] = make_float2(f0, f1);
}

// ---- fused: dense levels 0..4 inline (L2-resident tables) + staged hashed + MLP ----
// Dense TA-bound gathers overlap with MLP VALU on separate pipes; saves the
// 160 MB dense-enc round-trip and one dispatch.
__global__ void __launch_bounds__(256) mlp_dense_kernel(
    const float* __restrict__ p, const float* __restrict__ aabb,
    const float* __restrict__ table, const float2* __restrict__ enc,
    const float* __restrict__ w1, const float* __restrict__ w2,
    const float* __restrict__ w3, float* __restrict__ out,
    int N, ScaleArgs sa)
{
    const int i = blockIdx.x * 256 + threadIdx.x;
    if (i >= N) return;

    float e[32];

    // hashed levels first: issue the streaming loads early
#pragma unroll
    for (int l = 0; l < NHASH; ++l) {
        const float2 v = enc[(size_t)l * N + i];
        e[2 * (l + 5)]     = v.x;
        e[2 * (l + 5) + 1] = v.y;
    }

    // dense levels 0..4 inline
    const float3 u = normalize_pt(p, aabb, i);
    constexpr int DENSE_RES[5] = {16, 24, 34, 49, 71};
#pragma unroll
    for (int l = 0; l < 5; ++l) {
        const float s = sa.s[l];
        const float posx = u.x * s + 0.5f;
        const float posy = u.y * s + 0.5f;
        const float posz = u.z * s + 0.5f;
        const float flx = floorf(posx), fly = floorf(posy), flz = floorf(posz);
        const float fx = posx - flx, fy = posy - fly, fz = posz - flz;
        const int ix = (int)flx, iy = (int)fly, iz = (int)flz;

        const int res = DENSE_RES[l];
        const unsigned b  = (unsigned)(ix + res * (iy + res * iz));
        const unsigned dy = (unsigned)res;
        const unsigned dz = (unsigned)(res * res);

        const float2* __restrict__ tl =
            reinterpret_cast<const float2*>(table) + (size_t)l * T_SIZE;
        const float2 c0 = tl[b],           c1 = tl[b + 1u];
        const float2 c2 = tl[b + dy],      c3 = tl[b + dy + 1u];
        const float2 c4 = tl[b + dz],      c5 = tl[b + dz + 1u];
        const float2 c6 = tl[b + dy + dz], c7 = tl[b + dy + dz + 1u];

        float f0, f1;
        tri_acc(c0, c1, c2, c3, c4, c5, c6, c7, fx, fy, fz, f0, f1);
        e[2 * l] = f0; e[2 * l + 1] = f1;
    }

    // MLP (weights via wave-uniform s_load + SGPR-operand FMA)
    float h[32];
#pragma unroll
    for (int j = 0; j < 32; ++j) {
        float acc = 0.0f;
#pragma unroll
        for (int k = 0; k < 32; ++k) acc = fmaf(w1[32 * j + k], e[k], acc);
        h[j] = fmaxf(acc, 0.0f);
    }
    float g[32];
#pragma unroll
    for (int j = 0; j < 32; ++j) {
        float acc = 0.0f;
#pragma unroll
        for (int k = 0; k < 32; ++k) acc = fmaf(w2[32 * j + k], h[k], acc);
        g[j] = fmaxf(acc, 0.0f);
    }
    float o[4];
#pragma unroll
    for (int j = 0; j < 4; ++j) {
        float acc = 0.0f;
#pragma unroll
        for (int k = 0; k < 32; ++k) acc = fmaf(w3[32 * j + k], g[k], acc);
        o[j] = acc;
    }
    reinterpret_cast<float4*>(out)[i] = make_float4(o[0], o[1], o[2], o[3]);
}

// ---- fallback: fully fused kernel (used only if ws too small) ----
__global__ void __launch_bounds__(256) hashgrid_mlp_kernel(
    const float* __restrict__ p, const float* __restrict__ aabb,
    const float* __restrict__ table,
    const float* __restrict__ w1, const float* __restrict__ w2,
    const float* __restrict__ w3, float* __restrict__ out,
    int N, ScaleArgs sa)
{
    const int i = blockIdx.x * 256 + threadIdx.x;
    if (i >= N) return;
    const float3 u = normalize_pt(p, aabb, i);

    float enc[2 * NLV];
    constexpr int DENSE_RES[5] = {16, 24, 34, 49, 71};
#pragma unroll
    for (int l = 0; l < NLV; ++l) {
        const float s = sa.s[l];
        const float posx = u.x * s + 0.5f;
        const float posy = u.y * s + 0.5f;
        const float posz = u.z * s + 0.5f;
        const float flx = floorf(posx), fly = floorf(posy), flz = floorf(posz);
        const float fx = posx - flx, fy = posy - fly, fz = posz - flz;
        const int ix = (int)flx, iy = (int)fly, iz = (int)flz;

        unsigned idx0, idx1, idx2, idx3, idx4, idx5, idx6, idx7;
        if (l < 5) {
            const int res = DENSE_RES[l];
            const unsigned b  = (unsigned)(ix + res * (iy + res * iz));
            const unsigned dy = (unsigned)res;
            const unsigned dz = (unsigned)(res * res);
            idx0 = b;           idx1 = b + 1u;
            idx2 = b + dy;      idx3 = b + dy + 1u;
            idx4 = b + dz;      idx5 = b + dz + 1u;
            idx6 = b + dy + dz; idx7 = b + dy + dz + 1u;
        } else {
            const unsigned hx0 = (unsigned)ix,               hx1 = hx0 + 1u;
            const unsigned hy0 = (unsigned)iy * 2654435761u, hy1 = hy0 + 2654435761u;
            const unsigned hz0 = (unsigned)iz * 805459861u,  hz1 = hz0 + 805459861u;
            idx0 = (hx0 ^ hy0 ^ hz0) & T_MASK;
            idx1 = (hx1 ^ hy0 ^ hz0) & T_MASK;
            idx2 = (hx0 ^ hy1 ^ hz0) & T_MASK;
            idx3 = (hx1 ^ hy1 ^ hz0) & T_MASK;
            idx4 = (hx0 ^ hy0 ^ hz1) & T_MASK;
            idx5 = (hx1 ^ hy0 ^ hz1) & T_MASK;
            idx6 = (hx0 ^ hy1 ^ hz1) & T_MASK;
            idx7 = (hx1 ^ hy1 ^ hz1) & T_MASK;
        }

        const float2* __restrict__ tl =
            reinterpret_cast<const float2*>(table) + (size_t)l * T_SIZE;
        const float2 c0 = tl[idx0], c1 = tl[idx1], c2 = tl[idx2], c3 = tl[idx3];
        const float2 c4 = tl[idx4], c5 = tl[idx5], c6 = tl[idx6], c7 = tl[idx7];

        float f0, f1;
        tri_acc(c0, c1, c2, c3, c4, c5, c6, c7, fx, fy, fz, f0, f1);
        enc[2 * l] = f0; enc[2 * l + 1] = f1;
    }

    float h[32];
#pragma unroll
    for (int j = 0; j < 32; ++j) {
        float acc = 0.0f;
#pragma unroll
        for (int k = 0; k < 32; ++k) acc = fmaf(w1[32 * j + k], enc[k], acc);
        h[j] = fmaxf(acc, 0.0f);
    }
    float g[32];
#pragma unroll
    for (int j = 0; j < 32; ++j) {
        float acc = 0.0f;
#pragma unroll
        for (int k = 0; k < 32; ++k) acc = fmaf(w2[32 * j + k], h[k], acc);
        g[j] = fmaxf(acc, 0.0f);
    }
    float o[4];
#pragma unroll
    for (int j = 0; j < 4; ++j) {
        float acc = 0.0f;
#pragma unroll
        for (int k = 0; k < 32; ++k) acc = fmaf(w3[32 * j + k], g[k], acc);
        o[j] = acc;
    }
    reinterpret_cast<float4*>(out)[i] = make_float4(o[0], o[1], o[2], o[3]);
}

extern "C" void kernel_launch(void* const* d_in, const int* in_sizes, int n_in,
                              void* d_out, int out_size, void* d_ws, size_t ws_size,
                              hipStream_t stream) {
    const float* p     = (const float*)d_in[0];
    const float* aabb  = (const float*)d_in[1];
    const float* table = (const float*)d_in[2];
    const float* w1    = (const float*)d_in[3];
    const float* w2    = (const float*)d_in[4];
    const float* w3    = (const float*)d_in[5];
    float* out = (float*)d_out;
    const int N = in_sizes[0] / 3;

    ScaleArgs sa;
    const double b = exp(log(4096.0 / 16.0) / (double)(NLV - 1));
    for (int l = 0; l < NLV; ++l) sa.s[l] = (float)(16.0 * pow(b, (double)l) - 1.0);

    const int threads = 256;
    const int blocks = (N + threads - 1) / threads;
    const size_t need = (size_t)N * NHASH * sizeof(float2);

    if (ws_size >= need) {
        float2* enc = (float2*)d_ws;
#define LAUNCH_HASH(L) \
        hipLaunchKernelGGL(hash_encode_kernel<L>, dim3(blocks), dim3(threads), 0, stream, \
                           p, aabb, table, enc, N, sa.s[L])
        LAUNCH_HASH(5);  LAUNCH_HASH(6);  LAUNCH_HASH(7);  LAUNCH_HASH(8);
        LAUNCH_HASH(9);  LAUNCH_HASH(10); LAUNCH_HASH(11); LAUNCH_HASH(12);
        LAUNCH_HASH(13); LAUNCH_HASH(14); LAUNCH_HASH(15);
#undef LAUNCH_HASH
        hipLaunchKernelGGL(mlp_dense_kernel, dim3(blocks), dim3(threads), 0, stream,
                           p, aabb, table, enc, w1, w2, w3, out, N, sa);
    } else {
        hipLaunchKernelGGL(hashgrid_mlp_kernel, dim3(blocks), dim3(threads), 0, stream,
                           p, aabb, table, w1, w2, w3, out, N, sa);
    }
}

// Round 13
// 908.849 us; speedup vs baseline: 1.2699x; 1.0481x over previous
//
#include <hip/hip_runtime.h>
#include <cmath>

#define NLV 16
static constexpr unsigned T_SIZE = 1u << 19;
static constexpr unsigned T_MASK = T_SIZE - 1u;
static constexpr int NHASH = 11;   // levels 5..15 staged in ws

struct ScaleArgs { float s[NLV]; };

typedef float v2f __attribute__((ext_vector_type(2)));

__device__ __forceinline__ void nt_store2(float2 v, float2* p) {
    v2f x; x[0] = v.x; x[1] = v.y;
    __builtin_nontemporal_store(x, (v2f*)p);
}
__device__ __forceinline__ v2f nt_load2v(const float2* p) {
    return __builtin_nontemporal_load((const v2f*)p);
}

__device__ __forceinline__ float3 normalize_pt(const float* __restrict__ p,
                                               const float* __restrict__ aabb, int i) {
    const float a0x = aabb[0], a0y = aabb[1], a0z = aabb[2];
    const float a1x = aabb[3], a1y = aabb[4], a1z = aabb[5];
    const float px = p[3 * i + 0], py = p[3 * i + 1], pz = p[3 * i + 2];
    float3 r;
    r.x = fminf(fmaxf((px - a0x) / (a1x - a0x), 0.0f), 1.0f);
    r.y = fminf(fmaxf((py - a0y) / (a1y - a0y), 0.0f), 1.0f);
    r.z = fminf(fmaxf((pz - a0z) / (a1z - a0z), 0.0f), 1.0f);
    return r;
}

// trilinear accumulate (same op order as reference)
__device__ __forceinline__ void tri_acc(
    float2 c0, float2 c1, float2 c2, float2 c3,
    float2 c4, float2 c5, float2 c6, float2 c7,
    float fx, float fy, float fz, float& f0, float& f1)
{
    const float wx0 = 1.0f - fx, wy0 = 1.0f - fy, wz0 = 1.0f - fz;
    const float w00 = wx0 * wy0, w10 = fx * wy0, w01 = wx0 * fy, w11 = fx * fy;
    const float wa = w00 * wz0, wb = w10 * wz0, wc = w01 * wz0, wd = w11 * wz0;
    const float we = w00 * fz,  wf = w10 * fz,  wg = w01 * fz,  wh = w11 * fz;

    f0 = wa * c0.x; f1 = wa * c0.y;
    f0 = fmaf(wb, c1.x, f0); f1 = fmaf(wb, c1.y, f1);
    f0 = fmaf(wc, c2.x, f0); f1 = fmaf(wc, c2.y, f1);
    f0 = fmaf(wd, c3.x, f0); f1 = fmaf(wd, c3.y, f1);
    f0 = fmaf(we, c4.x, f0); f1 = fmaf(we, c4.y, f1);
    f0 = fmaf(wf, c5.x, f0); f1 = fmaf(wf, c5.y, f1);
    f0 = fmaf(wg, c6.x, f0); f1 = fmaf(wg, c6.y, f1);
    f0 = fmaf(wh, c7.x, f0); f1 = fmaf(wh, c7.y, f1);
}

// ---- one hashed level per launch: 4 MiB slice == one XCD L2, phased ----
// enc store is NON-TEMPORAL so the 16 MB staging stream doesn't evict the
// phased table slice from L2 (single tail store -> no drain stall).
template<int L>
__global__ void __launch_bounds__(256) hash_encode_kernel(
    const float* __restrict__ p, const float* __restrict__ aabb,
    const float* __restrict__ table, float2* __restrict__ enc,
    int N, float s)
{
    const int i = blockIdx.x * 256 + threadIdx.x;
    if (i >= N) return;
    const float3 u = normalize_pt(p, aabb, i);

    const float posx = u.x * s + 0.5f;
    const float posy = u.y * s + 0.5f;
    const float posz = u.z * s + 0.5f;
    const float flx = floorf(posx), fly = floorf(posy), flz = floorf(posz);
    const float fx = posx - flx, fy = posy - fly, fz = posz - flz;
    const int ix = (int)flx, iy = (int)fly, iz = (int)flz;

    const unsigned hx0 = (unsigned)ix,               hx1 = hx0 + 1u;
    const unsigned hy0 = (unsigned)iy * 2654435761u, hy1 = hy0 + 2654435761u;
    const unsigned hz0 = (unsigned)iz * 805459861u,  hz1 = hz0 + 805459861u;
    const unsigned idx0 = (hx0 ^ hy0 ^ hz0) & T_MASK;
    const unsigned idx1 = (hx1 ^ hy0 ^ hz0) & T_MASK;
    const unsigned idx2 = (hx0 ^ hy1 ^ hz0) & T_MASK;
    const unsigned idx3 = (hx1 ^ hy1 ^ hz0) & T_MASK;
    const unsigned idx4 = (hx0 ^ hy0 ^ hz1) & T_MASK;
    const unsigned idx5 = (hx1 ^ hy0 ^ hz1) & T_MASK;
    const unsigned idx6 = (hx0 ^ hy1 ^ hz1) & T_MASK;
    const unsigned idx7 = (hx1 ^ hy1 ^ hz1) & T_MASK;

    const float2* __restrict__ tl =
        reinterpret_cast<const float2*>(table) + (size_t)L * T_SIZE;
    const float2 c0 = tl[idx0], c1 = tl[idx1], c2 = tl[idx2], c3 = tl[idx3];
    const float2 c4 = tl[idx4], c5 = tl[idx5], c6 = tl[idx6], c7 = tl[idx7];

    float f0, f1;
    tri_acc(c0, c1, c2, c3, c4, c5, c6, c7, fx, fy, fz, f0, f1);
    nt_store2(make_float2(f0, f1), &enc[(size_t)(L - 5) * N + i]);
}

// ---- fused: dense levels 0..4 inline + staged hashed (nt loads) + packed-fp32 MLP ----
__global__ void __launch_bounds__(256) mlp_dense_kernel(
    const float* __restrict__ p, const float* __restrict__ aabb,
    const float* __restrict__ table, const float2* __restrict__ enc,
    const float* __restrict__ w1, const float* __restrict__ w2,
    const float* __restrict__ w3, float* __restrict__ out,
    int N, ScaleArgs sa)
{
    const int i = blockIdx.x * 256 + threadIdx.x;
    if (i >= N) return;

    v2f e2[16];   // e2[k] = {e[2k], e[2k+1]}

    // hashed levels: nt streaming loads (read once; don't evict dense tables)
#pragma unroll
    for (int l = 0; l < NHASH; ++l) {
        e2[l + 5] = nt_load2v(&enc[(size_t)l * N + i]);
    }

    // dense levels 0..4 inline (tables 4.3 MB, L2-resident)
    const float3 u = normalize_pt(p, aabb, i);
    constexpr int DENSE_RES[5] = {16, 24, 34, 49, 71};
#pragma unroll
    for (int l = 0; l < 5; ++l) {
        const float s = sa.s[l];
        const float posx = u.x * s + 0.5f;
        const float posy = u.y * s + 0.5f;
        const float posz = u.z * s + 0.5f;
        const float flx = floorf(posx), fly = floorf(posy), flz = floorf(posz);
        const float fx = posx - flx, fy = posy - fly, fz = posz - flz;
        const int ix = (int)flx, iy = (int)fly, iz = (int)flz;

        const int res = DENSE_RES[l];
        const unsigned b  = (unsigned)(ix + res * (iy + res * iz));
        const unsigned dy = (unsigned)res;
        const unsigned dz = (unsigned)(res * res);

        const float2* __restrict__ tl =
            reinterpret_cast<const float2*>(table) + (size_t)l * T_SIZE;
        const float2 c0 = tl[b],           c1 = tl[b + 1u];
        const float2 c2 = tl[b + dy],      c3 = tl[b + dy + 1u];
        const float2 c4 = tl[b + dz],      c5 = tl[b + dz + 1u];
        const float2 c6 = tl[b + dy + dz], c7 = tl[b + dy + dz + 1u];

        float f0, f1;
        tri_acc(c0, c1, c2, c3, c4, c5, c6, c7, fx, fy, fz, f0, f1);
        e2[l][0] = f0; e2[l][1] = f1;
    }

    // ---- packed-fp32 MLP: v_pk_fma_f32, pairwise (even/odd) accumulation ----
    const v2f* __restrict__ w1v = reinterpret_cast<const v2f*>(w1);
    const v2f* __restrict__ w2v = reinterpret_cast<const v2f*>(w2);
    const v2f* __restrict__ w3v = reinterpret_cast<const v2f*>(w3);

    v2f h2[16];
#pragma unroll
    for (int j = 0; j < 32; ++j) {
        v2f acc = w1v[16 * j] * e2[0];
#pragma unroll
        for (int k = 1; k < 16; ++k)
            acc = __builtin_elementwise_fma(w1v[16 * j + k], e2[k], acc);
        const float hj = fmaxf(acc[0] + acc[1], 0.0f);
        h2[j >> 1][j & 1] = hj;
    }
    v2f g2[16];
#pragma unroll
    for (int j = 0; j < 32; ++j) {
        v2f acc = w2v[16 * j] * h2[0];
#pragma unroll
        for (int k = 1; k < 16; ++k)
            acc = __builtin_elementwise_fma(w2v[16 * j + k], h2[k], acc);
        const float gj = fmaxf(acc[0] + acc[1], 0.0f);
        g2[j >> 1][j & 1] = gj;
    }
    float o[4];
#pragma unroll
    for (int j = 0; j < 4; ++j) {
        v2f acc = w3v[16 * j] * g2[0];
#pragma unroll
        for (int k = 1; k < 16; ++k)
            acc = __builtin_elementwise_fma(w3v[16 * j + k], g2[k], acc);
        o[j] = acc[0] + acc[1];
    }
    reinterpret_cast<float4*>(out)[i] = make_float4(o[0], o[1], o[2], o[3]);
}

// ---- fallback: fully fused kernel (used only if ws too small) ----
__global__ void __launch_bounds__(256) hashgrid_mlp_kernel(
    const float* __restrict__ p, const float* __restrict__ aabb,
    const float* __restrict__ table,
    const float* __restrict__ w1, const float* __restrict__ w2,
    const float* __restrict__ w3, float* __restrict__ out,
    int N, ScaleArgs sa)
{
    const int i = blockIdx.x * 256 + threadIdx.x;
    if (i >= N) return;
    const float3 u = normalize_pt(p, aabb, i);

    float enc[2 * NLV];
    constexpr int DENSE_RES[5] = {16, 24, 34, 49, 71};
#pragma unroll
    for (int l = 0; l < NLV; ++l) {
        const float s = sa.s[l];
        const float posx = u.x * s + 0.5f;
        const float posy = u.y * s + 0.5f;
        const float posz = u.z * s + 0.5f;
        const float flx = floorf(posx), fly = floorf(posy), flz = floorf(posz);
        const float fx = posx - flx, fy = posy - fly, fz = posz - flz;
        const int ix = (int)flx, iy = (int)fly, iz = (int)flz;

        unsigned idx0, idx1, idx2, idx3, idx4, idx5, idx6, idx7;
        if (l < 5) {
            const int res = DENSE_RES[l];
            const unsigned b  = (unsigned)(ix + res * (iy + res * iz));
            const unsigned dy = (unsigned)res;
            const unsigned dz = (unsigned)(res * res);
            idx0 = b;           idx1 = b + 1u;
            idx2 = b + dy;      idx3 = b + dy + 1u;
            idx4 = b + dz;      idx5 = b + dz + 1u;
            idx6 = b + dy + dz; idx7 = b + dy + dz + 1u;
        } else {
            const unsigned hx0 = (unsigned)ix,               hx1 = hx0 + 1u;
            const unsigned hy0 = (unsigned)iy * 2654435761u, hy1 = hy0 + 2654435761u;
            const unsigned hz0 = (unsigned)iz * 805459861u,  hz1 = hz0 + 805459861u;
            idx0 = (hx0 ^ hy0 ^ hz0) & T_MASK;
            idx1 = (hx1 ^ hy0 ^ hz0) & T_MASK;
            idx2 = (hx0 ^ hy1 ^ hz0) & T_MASK;
            idx3 = (hx1 ^ hy1 ^ hz0) & T_MASK;
            idx4 = (hx0 ^ hy0 ^ hz1) & T_MASK;
            idx5 = (hx1 ^ hy0 ^ hz1) & T_MASK;
            idx6 = (hx0 ^ hy1 ^ hz1) & T_MASK;
            idx7 = (hx1 ^ hy1 ^ hz1) & T_MASK;
        }

        const float2* __restrict__ tl =
            reinterpret_cast<const float2*>(table) + (size_t)l * T_SIZE;
        const float2 c0 = tl[idx0], c1 = tl[idx1], c2 = tl[idx2], c3 = tl[idx3];
        const float2 c4 = tl[idx4], c5 = tl[idx5], c6 = tl[idx6], c7 = tl[idx7];

        float f0, f1;
        tri_acc(c0, c1, c2, c3, c4, c5, c6, c7, fx, fy, fz, f0, f1);
        enc[2 * l] = f0; enc[2 * l + 1] = f1;
    }

    float h[32];
#pragma unroll
    for (int j = 0; j < 32; ++j) {
        float acc = 0.0f;
#pragma unroll
        for (int k = 0; k < 32; ++k) acc = fmaf(w1[32 * j + k], enc[k], acc);
        h[j] = fmaxf(acc, 0.0f);
    }
    float g[32];
#pragma unroll
    for (int j = 0; j < 32; ++j) {
        float acc = 0.0f;
#pragma unroll
        for (int k = 0; k < 32; ++k) acc = fmaf(w2[32 * j + k], h[k], acc);
        g[j] = fmaxf(acc, 0.0f);
    }
    float o[4];
#pragma unroll
    for (int j = 0; j < 4; ++j) {
        float acc = 0.0f;
#pragma unroll
        for (int k = 0; k < 32; ++k) acc = fmaf(w3[32 * j + k], g[k], acc);
        o[j] = acc;
    }
    reinterpret_cast<float4*>(out)[i] = make_float4(o[0], o[1], o[2], o[3]);
}

extern "C" void kernel_launch(void* const* d_in, const int* in_sizes, int n_in,
                              void* d_out, int out_size, void* d_ws, size_t ws_size,
                              hipStream_t stream) {
    const float* p     = (const float*)d_in[0];
    const float* aabb  = (const float*)d_in[1];
    const float* table = (const float*)d_in[2];
    const float* w1    = (const float*)d_in[3];
    const float* w2    = (const float*)d_in[4];
    const float* w3    = (const float*)d_in[5];
    float* out = (float*)d_out;
    const int N = in_sizes[0] / 3;

    ScaleArgs sa;
    const double b = exp(log(4096.0 / 16.0) / (double)(NLV - 1));
    for (int l = 0; l < NLV; ++l) sa.s[l] = (float)(16.0 * pow(b, (double)l) - 1.0);

    const int threads = 256;
    const int blocks = (N + threads - 1) / threads;
    const size_t need = (size_t)N * NHASH * sizeof(float2);

    if (ws_size >= need) {
        float2* enc = (float2*)d_ws;
#define LAUNCH_HASH(L) \
        hipLaunchKernelGGL(hash_encode_kernel<L>, dim3(blocks), dim3(threads), 0, stream, \
                           p, aabb, table, enc, N, sa.s[L])
        LAUNCH_HASH(5);  LAUNCH_HASH(6);  LAUNCH_HASH(7);  LAUNCH_HASH(8);
        LAUNCH_HASH(9);  LAUNCH_HASH(10); LAUNCH_HASH(11); LAUNCH_HASH(12);
        LAUNCH_HASH(13); LAUNCH_HASH(14); LAUNCH_HASH(15);
#undef LAUNCH_HASH
        hipLaunchKernelGGL(mlp_dense_kernel, dim3(blocks), dim3(threads), 0, stream,
                           p, aabb, table, enc, w1, w2, w3, out, N, sa);
    } else {
        hipLaunchKernelGGL(hashgrid_mlp_kernel, dim3(blocks), dim3(threads), 0, stream,
                           p, aabb, table, w1, w2, w3, out, N, sa);
    }
}